// Round 2
// baseline (976.023 us; speedup 1.0000x reference)
//
#include <hip/hip_runtime.h>

typedef __attribute__((ext_vector_type(8))) short short8v;
typedef __attribute__((ext_vector_type(4))) float f32x4;

#define IN_CH 128
#define HID   256
#define HEADS 8
#define NCLS  64
#define LDO   1088   // JK output row stride in floats: 256*4 + 64
#define LDOU  2176   // same stride in ushorts (bf16 slots)

__device__ __forceinline__ unsigned short f2b(float f) {
    unsigned u = __float_as_uint(f);
    u += 0x7FFFu + ((u >> 16) & 1u);      // RNE to bf16
    return (unsigned short)(u >> 16);
}
__device__ __forceinline__ float b2f(unsigned short s) {
    return __uint_as_float(((unsigned)s) << 16);
}

// ---------------- edge-index int64/int32 layout detection ----------------
__global__ void detect64(const int* __restrict__ ei, int* __restrict__ flag, int E) {
    __shared__ int nz;
    if (threadIdx.x == 0) nz = 0;
    __syncthreads();
    int v = ei[2 * threadIdx.x + 1];   // odd words: high halves if data is int64
    if (v != 0) atomicAdd(&nz, 1);
    __syncthreads();
    if (threadIdx.x == 0) flag[0] = (nz == 0) ? 1 : 0;
}

// ---------------- CSR build over the E real edges (self-loops analytic) ----------------
__global__ void hist_k(const int* __restrict__ ei, const int* __restrict__ flag,
                       int* __restrict__ deg, int E) {
    int i = blockIdx.x * 256 + threadIdx.x;
    if (i >= E) return;
    int is64 = flag[0];
    int dst = is64 ? ei[2 * (E + i)] : ei[E + i];
    atomicAdd(&deg[dst], 1);
}

__global__ void scan_k(const int* __restrict__ deg, int* __restrict__ rowptr, int N) {
    __shared__ int sums[1024];
    int t = threadIdx.x;
    int chunk = (N + 1023) >> 10;
    int beg = t * chunk;
    int end = beg + chunk; if (end > N) end = N;
    if (beg > N) beg = N;
    int s = 0;
    for (int i = beg; i < end; ++i) s += deg[i];
    sums[t] = s;
    __syncthreads();
    for (int o = 1; o < 1024; o <<= 1) {
        int v = (t >= o) ? sums[t - o] : 0;
        __syncthreads();
        sums[t] += v;
        __syncthreads();
    }
    int run = (t == 0) ? 0 : sums[t - 1];
    for (int i = beg; i < end; ++i) { rowptr[i] = run; run += deg[i]; }
    if (t == 1023) rowptr[N] = sums[1023];
}

__global__ void fill_k(const int* __restrict__ ei, const int* __restrict__ flag,
                       const int* __restrict__ rowptr, int* __restrict__ cnt,
                       int* __restrict__ colb, int E) {
    int i = blockIdx.x * 256 + threadIdx.x;
    if (i >= E) return;
    int is64 = flag[0];
    int src, dst;
    if (is64) { src = ei[2 * i]; dst = ei[2 * (E + i)]; }
    else      { src = ei[i];     dst = ei[E + i]; }
    int pos = rowptr[dst] + atomicAdd(&cnt[dst], 1);
    colb[pos] = src;
}

// ---------------- weight convert + transpose: W[K][N] f32 -> WT[N][K] bf16 ----------------
__global__ void convtw(const float* __restrict__ W, unsigned short* __restrict__ WT,
                       int K, int N) {
    int i = blockIdx.x * 256 + threadIdx.x;
    if (i >= K * N) return;
    int k = i / N, n = i - k * N;
    WT[(size_t)n * K + k] = f2b(W[i]);
}

// ---------------- bf16 MFMA GEMM: C[M,N] = A[M,K](f32,lda) * BT[N,K](bf16) ----------------
#define GBM 128
#define GBN 64
#define GBK 32
#define GLD 56   // 32 + 24 pad -> 112B row stride (16B-aligned, bank-friendly)

template<int OUTF32>
__global__ __launch_bounds__(256) void gemm_bf16(
    const float* __restrict__ A, int lda,
    const unsigned short* __restrict__ BT,
    int M, int N, int K,
    float* __restrict__ outF, const float* __restrict__ bias,
    unsigned short* __restrict__ outB, int ostride)
{
    __shared__ unsigned short Asm[GBM][GLD];
    __shared__ unsigned short Bsm[GBN][GLD];
    const int t = threadIdx.x;
    const int wid = t >> 6, lane = t & 63;
    const int m0 = blockIdx.x * GBM;
    const int n0 = blockIdx.y * GBN;
    const int wm = (wid >> 1) * 64;  // waves 2x2 -> wave tile 64x32
    const int wn = (wid & 1) * 32;

    f32x4 acc[4][2];
#pragma unroll
    for (int i = 0; i < 4; ++i)
#pragma unroll
        for (int j = 0; j < 2; ++j) acc[i][j] = (f32x4)0.f;

    const int ar = t >> 3;          // A staging: row 0..31 (+32*pass)
    const int ac = (t & 7) * 4;     // A staging: k col (float4)
    const int bc_ = t >> 2;         // B staging: col 0..63
    const int bk = (t & 3) * 8;     // B staging: k chunk (8 bf16 = 16B)
    const int kk = (lane >> 4) * 8; // fragment k offset
    const int rA = lane & 15;

    for (int k0 = 0; k0 < K; k0 += GBK) {
        __syncthreads();
#pragma unroll
        for (int p = 0; p < 4; ++p) {
            int row = ar + p * 32;
            int grow = m0 + row;
            float4 v = make_float4(0.f, 0.f, 0.f, 0.f);
            if (grow < M) v = *(const float4*)(A + (size_t)grow * lda + k0 + ac);
            ushort4 w4;
            w4.x = f2b(v.x); w4.y = f2b(v.y); w4.z = f2b(v.z); w4.w = f2b(v.w);
            *(ushort4*)&Asm[row][ac] = w4;
        }
        {
            int4 v = *(const int4*)(BT + (size_t)(n0 + bc_) * K + k0 + bk);
            *(int4*)&Bsm[bc_][bk] = v;
        }
        __syncthreads();
        short8v af[4], bfr[2];
#pragma unroll
        for (int i = 0; i < 4; ++i) af[i] = *(const short8v*)&Asm[wm + i * 16 + rA][kk];
#pragma unroll
        for (int j = 0; j < 2; ++j) bfr[j] = *(const short8v*)&Bsm[wn + j * 16 + rA][kk];
#pragma unroll
        for (int i = 0; i < 4; ++i)
#pragma unroll
            for (int j = 0; j < 2; ++j)
                acc[i][j] = __builtin_amdgcn_mfma_f32_16x16x32_bf16(af[i], bfr[j], acc[i][j], 0, 0, 0);
    }

    const int cr = (lane >> 4) * 4;
    const int cc = lane & 15;
#pragma unroll
    for (int i = 0; i < 4; ++i)
#pragma unroll
        for (int j = 0; j < 2; ++j)
#pragma unroll
            for (int r = 0; r < 4; ++r) {
                int row = m0 + wm + i * 16 + cr + r;
                int col = n0 + wn + j * 16 + cc;
                if (row < M) {
                    float v = acc[i][j][r];
                    if (OUTF32) outF[(size_t)row * LDO + col] = v + bias[col];
                    else        outB[(size_t)row * ostride + col] = f2b(v);
                }
            }
}

// ---------------- per-node attention logits: alpha[n][h] = sum_c t[n,h,c]*a[h,c] ----------------
__global__ void alpha8(const unsigned short* __restrict__ tb, int tstride,
                       const float* __restrict__ as_, const float* __restrict__ ad_,
                       float* __restrict__ aS, float* __restrict__ aD, int n) {
    int wid = threadIdx.x >> 6, lane = threadIdx.x & 63;
    int node = blockIdx.x * 4 + wid;
    if (node >= n) return;
    int c = lane * 4;  // head = c/32 = lane>>3
    ushort4 hv = *(const ushort4*)(tb + (size_t)node * tstride + c);
    float4 av = *(const float4*)(as_ + c);
    float4 dv = *(const float4*)(ad_ + c);
    float h0 = b2f(hv.x), h1 = b2f(hv.y), h2 = b2f(hv.z), h3 = b2f(hv.w);
    float s = h0 * av.x + h1 * av.y + h2 * av.z + h3 * av.w;
    float d = h0 * dv.x + h1 * dv.y + h2 * dv.z + h3 * dv.w;
    s += __shfl_xor(s, 1); s += __shfl_xor(s, 2); s += __shfl_xor(s, 4);
    d += __shfl_xor(d, 1); d += __shfl_xor(d, 2); d += __shfl_xor(d, 4);
    if ((lane & 7) == 0) {
        aS[node * HEADS + (lane >> 3)] = s;
        aD[node * HEADS + (lane >> 3)] = d;
    }
}

__global__ void alpha1(const unsigned short* __restrict__ tb64, int tstride,
                       const float* __restrict__ as_, const float* __restrict__ ad_,
                       float* __restrict__ aS, float* __restrict__ aD, int n) {
    int wid = threadIdx.x >> 6, lane = threadIdx.x & 63;
    int node = blockIdx.x * 4 + wid;
    if (node >= n) return;
    float v = b2f(tb64[(size_t)node * tstride + lane]);
    float s = v * as_[lane], d = v * ad_[lane];
#pragma unroll
    for (int o = 1; o < 64; o <<= 1) { s += __shfl_xor(s, o); d += __shfl_xor(d, o); }
    if (lane == 0) { aS[node] = s; aD[node] = d; }
}

// ---------------- fused scatter-softmax + aggregation, one wave per dst node ----------------
// out[dst,:] = relu?( (sum_e w_e * t[src_e,:]) / (sum_e w_e) + bias ),
// w_e = exp(lrelu(aS[src]+aD[dst])); self-loop e=(dst,dst) included analytically.
__global__ void agg8(const int* __restrict__ rowptr, const int* __restrict__ colb,
                     const float* __restrict__ aS, const float* __restrict__ aD,
                     const unsigned short* __restrict__ tb, int tstride,
                     const float* __restrict__ bias,
                     float* __restrict__ outp, int n, int dorelu) {
    int wid = threadIdx.x >> 6, lane = threadIdx.x & 63;
    int node = blockIdx.x * 4 + wid;
    if (node >= n) return;
    int c = lane * 4, head = lane >> 3;
    float aDv = aD[node * HEADS + head];
    // self-loop term
    float xs = aS[node * HEADS + head] + aDv;
    xs = xs > 0.f ? xs : 0.2f * xs;
    float wS = __expf(xs);
    float den = wS + 1e-16f;
    ushort4 hv0 = *(const ushort4*)(tb + (size_t)node * tstride + c);
    float a0 = wS * b2f(hv0.x), a1 = wS * b2f(hv0.y);
    float a2 = wS * b2f(hv0.z), a3 = wS * b2f(hv0.w);
    int s0 = rowptr[node], s1 = rowptr[node + 1];
    for (int e = s0; e < s1; ++e) {
        int src = colb[e];
        float xx = aS[src * HEADS + head] + aDv;
        xx = xx > 0.f ? xx : 0.2f * xx;
        float w = __expf(xx);
        den += w;
        ushort4 hv = *(const ushort4*)(tb + (size_t)src * tstride + c);
        a0 += w * b2f(hv.x); a1 += w * b2f(hv.y);
        a2 += w * b2f(hv.z); a3 += w * b2f(hv.w);
    }
    float inv = 1.f / den;
    float4 bv = *(const float4*)(bias + c);
    float o0 = a0 * inv + bv.x, o1 = a1 * inv + bv.y;
    float o2 = a2 * inv + bv.z, o3 = a3 * inv + bv.w;
    if (dorelu) {
        o0 = fmaxf(o0, 0.f); o1 = fmaxf(o1, 0.f);
        o2 = fmaxf(o2, 0.f); o3 = fmaxf(o3, 0.f);
    }
    *(float4*)(outp + (size_t)node * LDO + c) = make_float4(o0, o1, o2, o3);
}

__global__ void agg1(const int* __restrict__ rowptr, const int* __restrict__ colb,
                     const float* __restrict__ aS, const float* __restrict__ aD,
                     const unsigned short* __restrict__ tb64, int tstride,
                     const float* __restrict__ bl,
                     float* __restrict__ outp, int n) {
    int wid = threadIdx.x >> 6, lane = threadIdx.x & 63;
    int node = blockIdx.x * 4 + wid;
    if (node >= n) return;
    float aDv = aD[node];
    float xs = aS[node] + aDv;
    xs = xs > 0.f ? xs : 0.2f * xs;
    float wS = __expf(xs);
    float den = wS + 1e-16f;
    float acc = wS * b2f(tb64[(size_t)node * tstride + lane]);
    int s0 = rowptr[node], s1 = rowptr[node + 1];
    for (int e = s0; e < s1; ++e) {
        int src = colb[e];
        float xx = aS[src] + aDv;
        xx = xx > 0.f ? xx : 0.2f * xx;
        float w = __expf(xx);
        den += w;
        acc += w * b2f(tb64[(size_t)src * tstride + lane]);
    }
    outp[(size_t)node * LDO + 1024 + lane] = acc / den + bl[lane];
}

// ---------------- host launcher ----------------
extern "C" void kernel_launch(void* const* d_in, const int* in_sizes, int n_in,
                              void* d_out, int out_size, void* d_ws, size_t ws_size,
                              hipStream_t stream) {
    const float* x   = (const float*)d_in[0];
    const int*   ei  = (const int*)d_in[1];
    const float* W0  = (const float*)d_in[2];
    const float* b0  = (const float*)d_in[3];
    const float* Wc  = (const float*)d_in[4];
    const float* asc = (const float*)d_in[5];
    const float* adc = (const float*)d_in[6];
    const float* bc  = (const float*)d_in[7];
    const float* Wl  = (const float*)d_in[8];
    const float* asl = (const float*)d_in[9];
    const float* adl = (const float*)d_in[10];
    const float* bl  = (const float*)d_in[11];
    float* out = (float*)d_out;
    unsigned short* outU = (unsigned short*)d_out;

    const int N = in_sizes[0] / IN_CH;   // 50000
    const int E = in_sizes[1] / 2;       // 800000

    // t staging lives inside d_out's not-yet-final columns (bf16 packed):
    //  t0 -> f32-cols [896,1024)  (future h3 slot; dead before agg2 writes h3)
    //  t1 -> f32-cols [768,896)   (ditto)
    //  t2 -> f32-cols [0,128)     (over h0; h0 re-derived at the end)
    //  tF -> f32-cols [128,192)
    unsigned short* t0 = outU + 896 * 2;
    unsigned short* t1 = outU + 768 * 2;
    unsigned short* t2 = outU;
    unsigned short* tF = outU + 128 * 2;

    // workspace (~7.3 MB total -- must stay small; overflowing d_ws clobbers
    // the harness's pristine input copies and poisons every later call)
    char* ws = (char*)d_ws;
    size_t off = 0;
    auto take = [&](size_t bytes) -> void* {
        void* p = ws + off;
        off += (bytes + 255) & ~(size_t)255;
        return p;
    };
    unsigned short* WbT = (unsigned short*)take((size_t)245760 * 2);
    float* aS   = (float*)take((size_t)N * HEADS * 4);
    float* aD   = (float*)take((size_t)N * HEADS * 4);
    int* deg    = (int*)take((size_t)N * 4);
    int* cnt    = (int*)take((size_t)N * 4);
    int* rowptr = (int*)take((size_t)(N + 1) * 4);
    int* colb   = (int*)take((size_t)E * 4);
    int* flag   = (int*)take(256);

    unsigned short* W0T  = WbT;
    unsigned short* WcT0 = WbT + 32768;             // 3 x [256][256]
    unsigned short* WlT  = WbT + 32768 + 3 * 65536; // [64][256]

    hipMemsetAsync(deg, 0, (size_t)N * 4, stream);
    hipMemsetAsync(cnt, 0, (size_t)N * 4, stream);

    detect64<<<1, 256, 0, stream>>>(ei, flag, E);
    convtw<<<(32768 + 255) / 256, 256, 0, stream>>>(W0, W0T, 128, 256);
    for (int l = 0; l < 3; ++l)
        convtw<<<(65536 + 255) / 256, 256, 0, stream>>>(Wc + l * 65536, WcT0 + l * 65536, 256, 256);
    convtw<<<(16384 + 255) / 256, 256, 0, stream>>>(Wl, WlT, 256, 64);

    hist_k<<<(E + 255) / 256, 256, 0, stream>>>(ei, flag, deg, E);
    scan_k<<<1, 1024, 0, stream>>>(deg, rowptr, N);
    fill_k<<<(E + 255) / 256, 256, 0, stream>>>(ei, flag, rowptr, cnt, colb, E);

    const int gmx = (N + GBM - 1) / GBM;
    const int nwb = (N + 3) / 4;

    // h0 = x @ W0 + b0 -> out cols [0,256)
    gemm_bf16<1><<<dim3(gmx, 4), 256, 0, stream>>>(x, IN_CH, W0T, N, 256, 128, out, b0, nullptr, 0);

    unsigned short* tbs[3] = { t0, t1, t2 };
    for (int l = 0; l < 3; ++l) {
        gemm_bf16<0><<<dim3(gmx, 4), 256, 0, stream>>>(out + 256 * l, LDO, WcT0 + l * 65536,
                                                       N, 256, 256, nullptr, nullptr, tbs[l], LDOU);
        alpha8<<<nwb, 256, 0, stream>>>(tbs[l], LDOU, asc + l * 256, adc + l * 256, aS, aD, N);
        agg8<<<nwb, 256, 0, stream>>>(rowptr, colb, aS, aD, tbs[l], LDOU, bc + l * 256,
                                      out + 256 * (l + 1), N, 1);
    }

    // final layer: heads=1, C=64, no relu -> out cols [1024,1088)
    gemm_bf16<0><<<dim3(gmx, 1), 256, 0, stream>>>(out + 768, LDO, WlT, N, 64, 256, nullptr, nullptr, tF, LDOU);
    alpha1<<<nwb, 256, 0, stream>>>(tF, LDOU, asl, adl, aS, aD, N);
    agg1<<<nwb, 256, 0, stream>>>(rowptr, colb, aS, aD, tF, LDOU, bl, out, N);

    // re-derive h0 -> out cols [0,256) (t2/tF staging overwrote it)
    gemm_bf16<1><<<dim3(gmx, 4), 256, 0, stream>>>(x, IN_CH, W0T, N, 256, 128, out, b0, nullptr, 0);
}

// Round 3
// 867.371 us; speedup vs baseline: 1.1253x; 1.1253x over previous
//
#include <hip/hip_runtime.h>

typedef __attribute__((ext_vector_type(8))) short short8v;
typedef __attribute__((ext_vector_type(4))) float f32x4;

#define IN_CH 128
#define HID   256
#define HEADS 8
#define NCLS  64
#define LDO   1088   // JK output row stride in floats: 256*4 + 64
#define LDOU  2176   // same stride in ushorts (bf16 slots)

__device__ __forceinline__ unsigned short f2b(float f) {
    unsigned u = __float_as_uint(f);
    u += 0x7FFFu + ((u >> 16) & 1u);      // RNE to bf16
    return (unsigned short)(u >> 16);
}
__device__ __forceinline__ float b2f(unsigned short s) {
    return __uint_as_float(((unsigned)s) << 16);
}

// ---------------- edge-index int64/int32 layout detection ----------------
__global__ void detect64(const int* __restrict__ ei, int* __restrict__ flag, int E) {
    __shared__ int nz;
    if (threadIdx.x == 0) nz = 0;
    __syncthreads();
    int v = ei[2 * threadIdx.x + 1];   // odd words: high halves if data is int64
    if (v != 0) atomicAdd(&nz, 1);
    __syncthreads();
    if (threadIdx.x == 0) flag[0] = (nz == 0) ? 1 : 0;
}

// ---------------- CSR build over the E real edges (self-loops analytic) ----------------
__global__ void hist_k(const int* __restrict__ ei, const int* __restrict__ flag,
                       int* __restrict__ deg, int E) {
    int i = blockIdx.x * 256 + threadIdx.x;
    if (i >= E) return;
    int is64 = flag[0];
    int dst = is64 ? ei[2 * (E + i)] : ei[E + i];
    atomicAdd(&deg[dst], 1);
}

__global__ void scan_k(const int* __restrict__ deg, int* __restrict__ rowptr, int N) {
    __shared__ int sums[1024];
    int t = threadIdx.x;
    int chunk = (N + 1023) >> 10;
    int beg = t * chunk;
    int end = beg + chunk; if (end > N) end = N;
    if (beg > N) beg = N;
    int s = 0;
    for (int i = beg; i < end; ++i) s += deg[i];
    sums[t] = s;
    __syncthreads();
    for (int o = 1; o < 1024; o <<= 1) {
        int v = (t >= o) ? sums[t - o] : 0;
        __syncthreads();
        sums[t] += v;
        __syncthreads();
    }
    int run = (t == 0) ? 0 : sums[t - 1];
    for (int i = beg; i < end; ++i) { rowptr[i] = run; run += deg[i]; }
    if (t == 1023) rowptr[N] = sums[1023];
}

__global__ void fill_k(const int* __restrict__ ei, const int* __restrict__ flag,
                       const int* __restrict__ rowptr, int* __restrict__ cnt,
                       int* __restrict__ colb, int E) {
    int i = blockIdx.x * 256 + threadIdx.x;
    if (i >= E) return;
    int is64 = flag[0];
    int src, dst;
    if (is64) { src = ei[2 * i]; dst = ei[2 * (E + i)]; }
    else      { src = ei[i];     dst = ei[E + i]; }
    int pos = rowptr[dst] + atomicAdd(&cnt[dst], 1);
    colb[pos] = src;
}

// ---------------- fused weight convert+transpose: all W -> WT[N][K] bf16 ----------------
__global__ void convw_all(const float* __restrict__ W0, const float* __restrict__ Wc,
                          const float* __restrict__ Wl,
                          unsigned short* __restrict__ W0T, unsigned short* __restrict__ WcT,
                          unsigned short* __restrict__ WlT) {
    int i = blockIdx.x * 256 + threadIdx.x;
    if (i < 32768) {                       // W0 [128][256]
        int k = i >> 8, n = i & 255;
        W0T[n * 128 + k] = f2b(W0[i]);
    } else if (i < 229376) {               // Wc [3][256][256]
        int j = i - 32768;
        int l = j >> 16, r = j & 65535;
        int k = r >> 8, n = r & 255;
        WcT[l * 65536 + n * 256 + k] = f2b(Wc[j]);
    } else if (i < 245760) {               // Wl [256][64]
        int j = i - 229376;
        int k = j >> 6, n = j & 63;
        WlT[n * 256 + k] = f2b(Wl[j]);
    }
}

// ---------------- x f32 -> bf16 (staged into d_out dead columns) ----------------
__global__ void convx(const float* __restrict__ x, unsigned short* __restrict__ xb, int n) {
    int idx = blockIdx.x * 256 + threadIdx.x;   // one float4 each
    int node = idx >> 5, c = (idx & 31) * 4;
    if (node >= n) return;
    float4 v = *(const float4*)(x + (size_t)node * IN_CH + c);
    ushort4 w;
    w.x = f2b(v.x); w.y = f2b(v.y); w.z = f2b(v.z); w.w = f2b(v.w);
    *(ushort4*)(xb + (size_t)node * LDOU + c) = w;
}

// ---------------- bf16 MFMA GEMM: C[M,64*gridy] = A[M,K] * BT[N][K](bf16) ----------------
// AF32: A is f32 (convert while staging); else A is bf16 (pure int4 copy).
// MODE 0: write bf16 t to outB. MODE 1: write f32 out+bias. MODE 2: MODE1 + bf16 copy.
#define GBM 128
#define GBN 64
#define GBK 64
#define GLD 72   // 64 + 8 pad shorts -> 144B row stride

template<int AF32, int MODE>
__global__ __launch_bounds__(256) void gemm_bf16(
    const void* __restrict__ Av, int lda,
    const unsigned short* __restrict__ BT,
    int M, int K,
    float* __restrict__ outF, const float* __restrict__ bias,
    unsigned short* __restrict__ outB, int ostride)
{
    __shared__ unsigned short Asm[GBM][GLD];
    __shared__ unsigned short Bsm[GBN][GLD];
    const int t = threadIdx.x;
    const int wid = t >> 6, lane = t & 63;
    const int m0 = blockIdx.x * GBM;
    const int n0 = blockIdx.y * GBN;
    const int wm = (wid >> 1) * 64;  // waves 2x2 -> wave tile 64x32
    const int wn = (wid & 1) * 32;

    f32x4 acc[4][2];
#pragma unroll
    for (int i = 0; i < 4; ++i)
#pragma unroll
        for (int j = 0; j < 2; ++j) acc[i][j] = (f32x4)0.f;

    const int rA = lane & 15;
    const int kk8 = (lane >> 4) * 8;

    for (int k0 = 0; k0 < K; k0 += GBK) {
        __syncthreads();
        if (AF32) {
            const float* A = (const float*)Av;
#pragma unroll
            for (int p = 0; p < 8; ++p) {
                int idx = p * 256 + t;
                int row = idx >> 4, c4 = (idx & 15) * 4;
                int grow = m0 + row;
                float4 v = make_float4(0.f, 0.f, 0.f, 0.f);
                if (grow < M) v = *(const float4*)(A + (size_t)grow * lda + k0 + c4);
                ushort4 w;
                w.x = f2b(v.x); w.y = f2b(v.y); w.z = f2b(v.z); w.w = f2b(v.w);
                *(ushort4*)&Asm[row][c4] = w;
            }
        } else {
            const unsigned short* A = (const unsigned short*)Av;
#pragma unroll
            for (int p = 0; p < 4; ++p) {
                int idx = p * 256 + t;
                int row = idx >> 3, ch = (idx & 7) * 8;
                int grow = m0 + row;
                int4 v = make_int4(0, 0, 0, 0);
                if (grow < M) v = *(const int4*)(A + (size_t)grow * lda + k0 + ch);
                *(int4*)&Asm[row][ch] = v;
            }
        }
#pragma unroll
        for (int p = 0; p < 2; ++p) {
            int idx = p * 256 + t;
            int row = idx >> 3, ch = (idx & 7) * 8;
            int4 v = *(const int4*)(BT + (size_t)(n0 + row) * K + k0 + ch);
            *(int4*)&Bsm[row][ch] = v;
        }
        __syncthreads();
#pragma unroll
        for (int s = 0; s < 2; ++s) {
            short8v af[4], bfv[2];
#pragma unroll
            for (int i = 0; i < 4; ++i) af[i] = *(const short8v*)&Asm[wm + i * 16 + rA][s * 32 + kk8];
#pragma unroll
            for (int j = 0; j < 2; ++j) bfv[j] = *(const short8v*)&Bsm[wn + j * 16 + rA][s * 32 + kk8];
#pragma unroll
            for (int i = 0; i < 4; ++i)
#pragma unroll
                for (int j = 0; j < 2; ++j)
                    acc[i][j] = __builtin_amdgcn_mfma_f32_16x16x32_bf16(af[i], bfv[j], acc[i][j], 0, 0, 0);
        }
    }

    const int cr = (lane >> 4) * 4;
    const int cc = lane & 15;
#pragma unroll
    for (int i = 0; i < 4; ++i)
#pragma unroll
        for (int j = 0; j < 2; ++j)
#pragma unroll
            for (int r = 0; r < 4; ++r) {
                int row = m0 + wm + i * 16 + cr + r;
                int col = n0 + wn + j * 16 + cc;
                if (row >= M) continue;
                float v = acc[i][j][r];
                if (MODE == 0) {
                    outB[(size_t)row * ostride + col] = f2b(v);
                } else {
                    v += bias[col];
                    outF[(size_t)row * LDO + col] = v;
                    if (MODE == 2) outB[(size_t)row * ostride + col] = f2b(v);
                }
            }
}

// ---------------- per-node attention logits ----------------
__global__ void alpha8(const unsigned short* __restrict__ tb, int tstride,
                       const float* __restrict__ as_, const float* __restrict__ ad_,
                       float* __restrict__ aS, float* __restrict__ aD, int n) {
    int wid = threadIdx.x >> 6, lane = threadIdx.x & 63;
    int node = blockIdx.x * 4 + wid;
    if (node >= n) return;
    int c = lane * 4;  // head = lane>>3
    ushort4 hv = *(const ushort4*)(tb + (size_t)node * tstride + c);
    float4 av = *(const float4*)(as_ + c);
    float4 dv = *(const float4*)(ad_ + c);
    float h0 = b2f(hv.x), h1 = b2f(hv.y), h2 = b2f(hv.z), h3 = b2f(hv.w);
    float s = h0 * av.x + h1 * av.y + h2 * av.z + h3 * av.w;
    float d = h0 * dv.x + h1 * dv.y + h2 * dv.z + h3 * dv.w;
    s += __shfl_xor(s, 1); s += __shfl_xor(s, 2); s += __shfl_xor(s, 4);
    d += __shfl_xor(d, 1); d += __shfl_xor(d, 2); d += __shfl_xor(d, 4);
    if ((lane & 7) == 0) {
        aS[node * HEADS + (lane >> 3)] = s;
        aD[node * HEADS + (lane >> 3)] = d;
    }
}

__global__ void alpha1(const unsigned short* __restrict__ tb64, int tstride,
                       const float* __restrict__ as_, const float* __restrict__ ad_,
                       float* __restrict__ aS, float* __restrict__ aD, int n) {
    int wid = threadIdx.x >> 6, lane = threadIdx.x & 63;
    int node = blockIdx.x * 4 + wid;
    if (node >= n) return;
    float v = b2f(tb64[(size_t)node * tstride + lane]);
    float s = v * as_[lane], d = v * ad_[lane];
#pragma unroll
    for (int o = 1; o < 64; o <<= 1) { s += __shfl_xor(s, o); d += __shfl_xor(d, o); }
    if (lane == 0) { aS[node] = s; aD[node] = d; }
}

// ---------------- fused scatter-softmax + aggregation, one wave per dst node ----------------
// out = relu?((self + sum_e w_e*t[src_e]) / (wS + sum w_e) + bias); dual bf16 copy to outb.
__global__ void agg8(const int* __restrict__ rowptr, const int* __restrict__ colb,
                     const float* __restrict__ aS, const float* __restrict__ aD,
                     const unsigned short* __restrict__ tb, int tstride,
                     const float* __restrict__ bias,
                     float* __restrict__ outp, unsigned short* __restrict__ outb,
                     int n, int dorelu) {
    int wid = threadIdx.x >> 6, lane = threadIdx.x & 63;
    int node = blockIdx.x * 4 + wid;
    if (node >= n) return;
    int c = lane * 4, head = lane >> 3;
    float aDv = aD[node * HEADS + head];
    float xs = aS[node * HEADS + head] + aDv;      // analytic self-loop
    xs = xs > 0.f ? xs : 0.2f * xs;
    float wS = __expf(xs);
    float den = wS + 1e-16f;
    ushort4 hv0 = *(const ushort4*)(tb + (size_t)node * tstride + c);
    float a0 = wS * b2f(hv0.x), a1 = wS * b2f(hv0.y);
    float a2 = wS * b2f(hv0.z), a3 = wS * b2f(hv0.w);
    int s0 = rowptr[node], s1 = rowptr[node + 1];
#pragma unroll 2
    for (int e = s0; e < s1; ++e) {
        int src = colb[e];
        float xx = aS[src * HEADS + head] + aDv;
        xx = xx > 0.f ? xx : 0.2f * xx;
        float w = __expf(xx);
        den += w;
        ushort4 hv = *(const ushort4*)(tb + (size_t)src * tstride + c);
        a0 += w * b2f(hv.x); a1 += w * b2f(hv.y);
        a2 += w * b2f(hv.z); a3 += w * b2f(hv.w);
    }
    float inv = 1.f / den;
    float4 bv = *(const float4*)(bias + c);
    float o0 = a0 * inv + bv.x, o1 = a1 * inv + bv.y;
    float o2 = a2 * inv + bv.z, o3 = a3 * inv + bv.w;
    if (dorelu) {
        o0 = fmaxf(o0, 0.f); o1 = fmaxf(o1, 0.f);
        o2 = fmaxf(o2, 0.f); o3 = fmaxf(o3, 0.f);
    }
    *(float4*)(outp + (size_t)node * LDO + c) = make_float4(o0, o1, o2, o3);
    ushort4 ob;
    ob.x = f2b(o0); ob.y = f2b(o1); ob.z = f2b(o2); ob.w = f2b(o3);
    *(ushort4*)(outb + (size_t)node * LDOU + c) = ob;
}

__global__ void agg1(const int* __restrict__ rowptr, const int* __restrict__ colb,
                     const float* __restrict__ aS, const float* __restrict__ aD,
                     const unsigned short* __restrict__ tb64, int tstride,
                     const float* __restrict__ bl,
                     float* __restrict__ outp, int n) {
    int wid = threadIdx.x >> 6, lane = threadIdx.x & 63;
    int node = blockIdx.x * 4 + wid;
    if (node >= n) return;
    float aDv = aD[node];
    float xs = aS[node] + aDv;
    xs = xs > 0.f ? xs : 0.2f * xs;
    float wS = __expf(xs);
    float den = wS + 1e-16f;
    float acc = wS * b2f(tb64[(size_t)node * tstride + lane]);
    int s0 = rowptr[node], s1 = rowptr[node + 1];
#pragma unroll 2
    for (int e = s0; e < s1; ++e) {
        int src = colb[e];
        float xx = aS[src] + aDv;
        xx = xx > 0.f ? xx : 0.2f * xx;
        float w = __expf(xx);
        den += w;
        acc += w * b2f(tb64[(size_t)src * tstride + lane]);
    }
    outp[(size_t)node * LDO + 1024 + lane] = acc / den + bl[lane];
}

// ---------------- host launcher ----------------
// d_out column choreography (f32-col units; ushort index = 2x):
//   convx:     write x_bf16          [256,320)
//   GEMM1:     read  [256,320) -> h0 f32 [0,256) + h0_bf16 [384,512)
//   GEMM(0):   read  [384,512) -> t0 bf16 [896,1024)
//   agg8(0):   read  t0 -> h1 f32 [256,512) (kills x_bf16,h0_bf16) + h1_bf16 [512,640)
//   GEMM(1):   read  [512,640) -> t1 bf16 [768,896)
//   agg8(1):   read  t1 -> h2 f32 [512,768) (kills h1_bf16) + h2_bf16 [896,1024) (kills t0)
//   GEMM(2):   read  [896,1024) -> t2 bf16 [0,128) (kills h0 f32 lower; re-derived)
//   agg8(2):   read  t2 -> h3 f32 [768,1024) (kills t1,h2_bf16) + h3_bf16 [128,256)
//   GEMMF:     read  [128,256) -> tF bf16 [0,32)   (kills part of t2; t2 dead)
//   agg1:      read  tF -> out f32 [1024,1088)
//   re-derive: read  x f32 -> h0 f32 [0,256) (kills t2,tF,h3_bf16; all dead)
extern "C" void kernel_launch(void* const* d_in, const int* in_sizes, int n_in,
                              void* d_out, int out_size, void* d_ws, size_t ws_size,
                              hipStream_t stream) {
    const float* x   = (const float*)d_in[0];
    const int*   ei  = (const int*)d_in[1];
    const float* W0  = (const float*)d_in[2];
    const float* b0  = (const float*)d_in[3];
    const float* Wc  = (const float*)d_in[4];
    const float* asc = (const float*)d_in[5];
    const float* adc = (const float*)d_in[6];
    const float* bc  = (const float*)d_in[7];
    const float* Wl  = (const float*)d_in[8];
    const float* asl = (const float*)d_in[9];
    const float* adl = (const float*)d_in[10];
    const float* bl  = (const float*)d_in[11];
    float* out = (float*)d_out;
    unsigned short* outU = (unsigned short*)d_out;

    const int N = in_sizes[0] / IN_CH;   // 50000
    const int E = in_sizes[1] / 2;       // 800000

    // workspace (~7.3 MB; keep small — overflow clobbers harness state)
    char* ws = (char*)d_ws;
    size_t off = 0;
    auto take = [&](size_t bytes) -> void* {
        void* p = ws + off;
        off += (bytes + 255) & ~(size_t)255;
        return p;
    };
    unsigned short* WbT = (unsigned short*)take((size_t)245760 * 2);
    float* aS   = (float*)take((size_t)N * HEADS * 4);
    float* aD   = (float*)take((size_t)N * HEADS * 4);
    int* deg    = (int*)take((size_t)N * 4);
    int* cnt    = (int*)take((size_t)N * 4);
    int* rowptr = (int*)take((size_t)(N + 1) * 4);
    int* colb   = (int*)take((size_t)E * 4);
    int* flag   = (int*)take(256);

    unsigned short* W0T = WbT;
    unsigned short* WcT = WbT + 32768;             // 3 x [256][256]
    unsigned short* WlT = WbT + 32768 + 3 * 65536; // [64][256]

    hipMemsetAsync(deg, 0, (size_t)N * 4, stream);
    hipMemsetAsync(cnt, 0, (size_t)N * 4, stream);

    detect64<<<1, 256, 0, stream>>>(ei, flag, E);
    convw_all<<<960, 256, 0, stream>>>(W0, Wc, Wl, W0T, WcT, WlT);
    convx<<<(N * 32 + 255) / 256, 256, 0, stream>>>(x, outU + 512, N);

    hist_k<<<(E + 255) / 256, 256, 0, stream>>>(ei, flag, deg, E);
    scan_k<<<1, 1024, 0, stream>>>(deg, rowptr, N);
    fill_k<<<(E + 255) / 256, 256, 0, stream>>>(ei, flag, rowptr, cnt, colb, E);

    const int gmx = (N + GBM - 1) / GBM;
    const int nwb = (N + 3) / 4;

    // h0 = x @ W0 + b0 -> f32 [0,256) + bf16 [384,512)
    gemm_bf16<0, 2><<<dim3(gmx, 4), 256, 0, stream>>>(outU + 512, LDOU, W0T, N, 128,
                                                      out, b0, outU + 768, LDOU);

    const unsigned short* Ab[3] = { outU + 768, outU + 1024, outU + 1792 };
    unsigned short* tbs[3]      = { outU + 1792, outU + 1536, outU };
    unsigned short* hb[3]       = { outU + 1024, outU + 1792, outU + 256 };
    for (int l = 0; l < 3; ++l) {
        gemm_bf16<0, 0><<<dim3(gmx, 4), 256, 0, stream>>>(Ab[l], LDOU, WcT + l * 65536, N, 256,
                                                          nullptr, nullptr, tbs[l], LDOU);
        alpha8<<<nwb, 256, 0, stream>>>(tbs[l], LDOU, asc + l * 256, adc + l * 256, aS, aD, N);
        agg8<<<nwb, 256, 0, stream>>>(rowptr, colb, aS, aD, tbs[l], LDOU, bc + l * 256,
                                      out + 256 * (l + 1), hb[l], N, 1);
    }

    // final layer: heads=1, C=64, no relu -> out cols [1024,1088)
    gemm_bf16<0, 0><<<dim3(gmx, 1), 256, 0, stream>>>(outU + 256, LDOU, WlT, N, 256,
                                                      nullptr, nullptr, outU, LDOU);
    alpha1<<<nwb, 256, 0, stream>>>(outU, LDOU, asl, adl, aS, aD, N);
    agg1<<<nwb, 256, 0, stream>>>(rowptr, colb, aS, aD, outU, LDOU, bl, out, N);

    // re-derive h0 f32 [0,256) (t2/tF/h3_bf16 staging overwrote it)
    gemm_bf16<1, 1><<<dim3(gmx, 4), 256, 0, stream>>>(x, IN_CH, W0T, N, 128,
                                                      out, b0, nullptr, 0);
}